// Round 2
// baseline (30511.786 us; speedup 1.0000x reference)
//
#include <hip/hip_runtime.h>
#include <cmath>

// (B, T, H) = (128, 1024, 512), fp32.
#define B_ 128
#define T_ 1024
#define H_ 512

// ---------------------------------------------------------------------------
// Phase 0: transpose Wh (512x512) into workspace: WhT[j][k] = Wh[k][j].
// Lets recurrence threads read contiguous float4 along k.
// ---------------------------------------------------------------------------
__global__ __launch_bounds__(256) void transpose512(
    const float* __restrict__ in, float* __restrict__ outT) {
  __shared__ float tile[32][33];  // +1 pad: conflict-free transpose
  const int bx = blockIdx.x * 32;
  const int by = blockIdx.y * 32;
  const int tx = threadIdx.x & 31;
  const int ty = (threadIdx.x >> 5) * 4;  // 8 groups of 4 rows
#pragma unroll
  for (int i = 0; i < 4; ++i)
    tile[ty + i][tx] = in[(size_t)(by + ty + i) * H_ + bx + tx];
  __syncthreads();
#pragma unroll
  for (int i = 0; i < 4; ++i)
    outT[(size_t)(bx + ty + i) * H_ + by + tx] = tile[tx][ty + i];
}

// ---------------------------------------------------------------------------
// Phase 1: out[t,b,:] = X[b,t,:] @ Wx + bias   (parallel GEMM, unchanged)
// ---------------------------------------------------------------------------
__global__ __launch_bounds__(256) void xw_gemm(const float* __restrict__ X,
                                               const float* __restrict__ Wx,
                                               const float* __restrict__ bias,
                                               float* __restrict__ out) {
  const int m0 = blockIdx.x * 64;
  const int n0 = blockIdx.y * 64;

  __shared__ float As[16][64];
  __shared__ float Bs[16][64];

  const int tid = threadIdx.x;
  const int ti = tid >> 4;
  const int tj = tid & 15;

  const int ra = tid >> 2;
  const int ca = (tid & 3) << 2;
  const int kb = tid >> 4;
  const int nb = (tid & 15) << 2;

  float acc[4][4] = {};

  for (int k0 = 0; k0 < H_; k0 += 16) {
    const float4 a4 =
        *reinterpret_cast<const float4*>(X + (size_t)(m0 + ra) * H_ + k0 + ca);
    As[ca + 0][ra] = a4.x;
    As[ca + 1][ra] = a4.y;
    As[ca + 2][ra] = a4.z;
    As[ca + 3][ra] = a4.w;
    *reinterpret_cast<float4*>(&Bs[kb][nb]) =
        *reinterpret_cast<const float4*>(Wx + (size_t)(k0 + kb) * H_ + n0 + nb);
    __syncthreads();

#pragma unroll
    for (int kk = 0; kk < 16; ++kk) {
      const float4 a = *reinterpret_cast<const float4*>(&As[kk][ti << 2]);
      const float4 b = *reinterpret_cast<const float4*>(&Bs[kk][tj << 2]);
      acc[0][0] = fmaf(a.x, b.x, acc[0][0]);
      acc[0][1] = fmaf(a.x, b.y, acc[0][1]);
      acc[0][2] = fmaf(a.x, b.z, acc[0][2]);
      acc[0][3] = fmaf(a.x, b.w, acc[0][3]);
      acc[1][0] = fmaf(a.y, b.x, acc[1][0]);
      acc[1][1] = fmaf(a.y, b.y, acc[1][1]);
      acc[1][2] = fmaf(a.y, b.z, acc[1][2]);
      acc[1][3] = fmaf(a.y, b.w, acc[1][3]);
      acc[2][0] = fmaf(a.z, b.x, acc[2][0]);
      acc[2][1] = fmaf(a.z, b.y, acc[2][1]);
      acc[2][2] = fmaf(a.z, b.z, acc[2][2]);
      acc[2][3] = fmaf(a.z, b.w, acc[2][3]);
      acc[3][0] = fmaf(a.w, b.x, acc[3][0]);
      acc[3][1] = fmaf(a.w, b.y, acc[3][1]);
      acc[3][2] = fmaf(a.w, b.z, acc[3][2]);
      acc[3][3] = fmaf(a.w, b.w, acc[3][3]);
    }
    __syncthreads();
  }

  const float4 bv = *reinterpret_cast<const float4*>(bias + n0 + (tj << 2));
#pragma unroll
  for (int ii = 0; ii < 4; ++ii) {
    const int m = m0 + (ti << 2) + ii;
    const int b = m >> 10;
    const int t = m & 1023;
    float4 v;
    v.x = acc[ii][0] + bv.x;
    v.y = acc[ii][1] + bv.y;
    v.z = acc[ii][2] + bv.z;
    v.w = acc[ii][3] + bv.w;
    *reinterpret_cast<float4*>(out + ((size_t)t * B_ + b) * H_ + n0 +
                               (tj << 2)) = v;
  }
}

// ---------------------------------------------------------------------------
// Phase 2: recurrence, in place on d_out.
// 64 WGs x 1024 threads; each WG owns 2 batch rows. Thread (j = tid&511,
// s = tid>>9) accumulates the k-half [s*256, s*256+256) for output column j,
// both rows. TR=true: W is WhT (row j contiguous in k -> float4 loads).
// Partials combined via LDS; s==0 thread adds xp (prefetched at step top,
// hidden behind k-loop), tanh, stores, updates LDS h.
// ---------------------------------------------------------------------------
template <bool TR>
__global__ __launch_bounds__(1024) void rnn_rec2(
    const float* __restrict__ state0, const float* __restrict__ W,
    float* __restrict__ out) {
  const int tid = threadIdx.x;
  const int j = tid & 511;
  const int s = tid >> 9;
  const int b0 = blockIdx.x * 2;
  const int b1 = b0 + 1;

  __shared__ float2 hh[H_];    // (h[b0][k], h[b1][k])
  __shared__ float2 part[H_];  // s==1 partial sums

  if (s == 0)
    hh[j] =
        make_float2(state0[(size_t)b0 * H_ + j], state0[(size_t)b1 * H_ + j]);
  __syncthreads();

  const int kbase = s * 256;

  for (int t = 0; t < T_; ++t) {
    float* o0 = out + (size_t)t * (B_ * H_) + (size_t)b0 * H_ + j;
    float* o1 = o0 + H_;
    float xp0 = 0.f, xp1 = 0.f;
    if (s == 0) {  // prefetch x@Wx+b; consumed only after the k-loop
      xp0 = *o0;
      xp1 = *o1;
    }

    float a0 = 0.f, a1 = 0.f;
    if (TR) {
      const float4* wp =
          reinterpret_cast<const float4*>(W + (size_t)j * H_ + kbase);
#pragma unroll 8
      for (int kk = 0; kk < 64; ++kk) {
        const float4 w = wp[kk];
        const float2 h0 = hh[kbase + 4 * kk + 0];
        const float2 h1 = hh[kbase + 4 * kk + 1];
        const float2 h2 = hh[kbase + 4 * kk + 2];
        const float2 h3 = hh[kbase + 4 * kk + 3];
        a0 = fmaf(w.x, h0.x, a0);
        a1 = fmaf(w.x, h0.y, a1);
        a0 = fmaf(w.y, h1.x, a0);
        a1 = fmaf(w.y, h1.y, a1);
        a0 = fmaf(w.z, h2.x, a0);
        a1 = fmaf(w.z, h2.y, a1);
        a0 = fmaf(w.w, h3.x, a0);
        a1 = fmaf(w.w, h3.y, a1);
      }
    } else {
      const float* wp = W + j;
#pragma unroll 8
      for (int k = 0; k < 256; ++k) {
        const float w = wp[(size_t)(kbase + k) * H_];
        const float2 h = hh[kbase + k];
        a0 = fmaf(w, h.x, a0);
        a1 = fmaf(w, h.y, a1);
      }
    }

    if (s == 1) part[j] = make_float2(a0, a1);
    __syncthreads();
    if (s == 0) {
      const float v0 = tanhf(a0 + part[j].x + xp0);
      const float v1 = tanhf(a1 + part[j].y + xp1);
      *o0 = v0;
      *o1 = v1;
      hh[j] = make_float2(v0, v1);
    }
    __syncthreads();
  }
}

extern "C" void kernel_launch(void* const* d_in, const int* in_sizes, int n_in,
                              void* d_out, int out_size, void* d_ws,
                              size_t ws_size, hipStream_t stream) {
  const float* X     = (const float*)d_in[0];  // [B, T, H]
  const float* state = (const float*)d_in[1];  // [1, B, H]
  const float* Wx    = (const float*)d_in[2];  // [H, H]
  const float* Wh    = (const float*)d_in[3];  // [H, H]
  const float* bias  = (const float*)d_in[4];  // [H]
  float* out = (float*)d_out;                  // [T, B, H]

  const bool use_tr = ws_size >= (size_t)H_ * H_ * sizeof(float);

  if (use_tr) {
    float* WhT = (float*)d_ws;
    hipLaunchKernelGGL(transpose512, dim3(16, 16), dim3(256), 0, stream, Wh,
                       WhT);
    hipLaunchKernelGGL(xw_gemm, dim3(2048, 8), dim3(256), 0, stream, X, Wx,
                       bias, out);
    hipLaunchKernelGGL((rnn_rec2<true>), dim3(64), dim3(1024), 0, stream,
                       state, WhT, out);
  } else {
    hipLaunchKernelGGL(xw_gemm, dim3(2048, 8), dim3(256), 0, stream, X, Wx,
                       bias, out);
    hipLaunchKernelGGL((rnn_rec2<false>), dim3(64), dim3(1024), 0, stream,
                       state, Wh, out);
  }
}